// Round 1
// baseline (1134.041 us; speedup 1.0000x reference)
//
#include <hip/hip_runtime.h>
#include <hip/hip_bf16.h>
#include <math.h>

#define NB 4
#define NN 4096
#define UU 512

using short8  = __attribute__((ext_vector_type(8))) short;
using bf16x8  = __attribute__((ext_vector_type(8))) __bf16;
using floatx4 = __attribute__((ext_vector_type(4))) float;

__device__ __forceinline__ floatx4 mfma16(short8 a, short8 b, floatx4 c) {
    return __builtin_amdgcn_mfma_f32_16x16x32_bf16(
        __builtin_bit_cast(bf16x8, a), __builtin_bit_cast(bf16x8, b), c, 0, 0, 0);
}

__device__ __forceinline__ unsigned short f2bf(float f) {
    union { float f; unsigned u; } v; v.f = f;
    return (unsigned short)((v.u + 0x7fffu + ((v.u >> 16) & 1u)) >> 16);
}
__device__ __forceinline__ float bf2f(unsigned short s) {
    union { unsigned u; float f; } v; v.u = ((unsigned)s) << 16; return v.f;
}

#define GLL16(gp, lp) __builtin_amdgcn_global_load_lds( \
    (const __attribute__((address_space(1))) void*)(gp), \
    (__attribute__((address_space(3))) void*)(lp), 16, 0, 0)

// ---------------------------------------------------------------- converts
__global__ void __launch_bounds__(256) k_cvt_x(const float* __restrict__ x,
                                               unsigned short* __restrict__ xb) {
    int i = (blockIdx.x * 256 + threadIdx.x) * 4;
    float4 v = *(const float4*)(x + i);
    ushort4 o;
    o.x = f2bf(v.x); o.y = f2bf(v.y); o.z = f2bf(v.z); o.w = f2bf(v.w);
    *(ushort4*)(xb + i) = o;
}

// WT[n*512+k] = bf16(W[k*512+n])
__global__ void __launch_bounds__(256) k_cvt_w(const float* __restrict__ W,
                                               unsigned short* __restrict__ WT) {
    int idx = blockIdx.x * 256 + threadIdx.x;  // 0..262143
    int n = idx >> 9, k = idx & 511;
    WT[idx] = f2bf(W[k * 512 + n]);
}

// ---------------------------------------------------------------- QKV proj
// C = Xb @ W (A.B^T form with WT), 128x128 tile, BK=32, z = 0:Q 1:K 2:V(transposed)
__global__ void __launch_bounds__(256, 2) k_proj(
    const unsigned short* __restrict__ Xb,
    const unsigned short* __restrict__ WqT, const unsigned short* __restrict__ WkT,
    const unsigned short* __restrict__ WvT,
    const float* __restrict__ bq, const float* __restrict__ bk, const float* __restrict__ bv,
    unsigned short* __restrict__ Q, unsigned short* __restrict__ K,
    unsigned short* __restrict__ Vt)
{
    __shared__ __align__(16) unsigned short As[128 * 32];
    __shared__ __align__(16) unsigned short Bs[128 * 32];
    const int z = blockIdx.z;
    const unsigned short* WT = (z == 0) ? WqT : (z == 1) ? WkT : WvT;
    const float* bias = (z == 0) ? bq : (z == 1) ? bk : bv;
    const int t = threadIdx.x, wave = t >> 6, lane = t & 63;
    const int quad = lane >> 4, l16 = lane & 15;
    const int m0 = blockIdx.x * 128, n0 = blockIdx.y * 128;
    const int wm = wave >> 1, wn = wave & 1;

    const int srow = wave * 32 + (lane >> 2);
    const int scol = (lane & 3) * 8;
    const unsigned short* gA = Xb + (size_t)(m0 + srow) * UU + scol;
    const unsigned short* gB = WT + (size_t)(n0 + srow) * UU + scol;
    unsigned short* lA = As + wave * 1024;
    unsigned short* lB = Bs + wave * 1024;

    floatx4 acc[4][4] = {};

    for (int k0 = 0; k0 < UU; k0 += 32) {
        GLL16(gA + k0, lA);
        GLL16(gA + k0 + 16 * UU, lA + 512);
        GLL16(gB + k0, lB);
        GLL16(gB + k0 + 16 * UU, lB + 512);
        __syncthreads();
        short8 a[4], b[4];
        #pragma unroll
        for (int i = 0; i < 4; i++)
            a[i] = *(const short8*)(As + (wm * 64 + i * 16 + l16) * 32 + quad * 8);
        #pragma unroll
        for (int j = 0; j < 4; j++)
            b[j] = *(const short8*)(Bs + (wn * 64 + j * 16 + l16) * 32 + quad * 8);
        #pragma unroll
        for (int i = 0; i < 4; i++)
            #pragma unroll
            for (int j = 0; j < 4; j++)
                acc[i][j] = mfma16(a[i], b[j], acc[i][j]);
        __syncthreads();
    }

    #pragma unroll
    for (int j = 0; j < 4; j++) {
        const int n = n0 + wn * 64 + j * 16 + l16;
        const float bv_ = bias[n];
        #pragma unroll
        for (int i = 0; i < 4; i++) {
            const int mb = m0 + wm * 64 + i * 16 + quad * 4;
            if (z < 2) {
                unsigned short* O = (z == 0) ? Q : K;
                #pragma unroll
                for (int r = 0; r < 4; r++)
                    O[(size_t)(mb + r) * UU + n] = f2bf(acc[i][j][r] + bv_);
            } else {
                const int bb = mb >> 12, tok = mb & (NN - 1);
                ushort4 o;
                o.x = f2bf(acc[i][j][0] + bv_);
                o.y = f2bf(acc[i][j][1] + bv_);
                o.z = f2bf(acc[i][j][2] + bv_);
                o.w = f2bf(acc[i][j][3] + bv_);
                *(ushort4*)(Vt + (size_t)bb * UU * NN + (size_t)n * NN + tok) = o;
            }
        }
    }
}

// ---------------------------------------------------------------- flash attention
// 8 waves: wave = (qt 0..3, kh/dh 0..1). BM=64 q rows per block, BN=64 keys/iter.
__global__ void __launch_bounds__(512, 1) k_flash(
    const unsigned short* __restrict__ Q,
    const unsigned short* __restrict__ K,
    const unsigned short* __restrict__ Vt,
    unsigned short* __restrict__ ctx)
{
    __shared__ __align__(16) float S_lds[64 * 68];          // stride 68 (16B-aligned rows, bank-spread)
    __shared__ __align__(16) unsigned short P_lds[64 * 72]; // stride 72 (16B-aligned rows, bank-spread)
    __shared__ float m_lds[64], l_lds[64], a_lds[64];

    const int b = blockIdx.y;
    const int q0 = blockIdx.x * 64;
    const int t = threadIdx.x;
    const int wave = t >> 6, lane = t & 63, quad = lane >> 4, l16 = lane & 15;
    const int qt = wave >> 1;   // q-tile 0..3
    const int kh = wave & 1;    // key half for S
    const int dh = wave & 1;    // d half for PV

    if (t < 64) { m_lds[t] = -INFINITY; l_lds[t] = 0.f; }

    // Q fragments for this wave's 16 q-rows, all 512 dims (64 VGPR)
    const unsigned short* qp = Q + (size_t)(b * NN + q0 + qt * 16 + l16) * UU + quad * 8;
    short8 qf[16];
    #pragma unroll
    for (int kk = 0; kk < 16; kk++) qf[kk] = *(const short8*)(qp + kk * 32);

    floatx4 o[16] = {};
    const float sscale = 0.04419417382415922f * 1.4426950408889634f;  // 1/sqrt(512)*log2(e)

    const unsigned short* Kb = K + (size_t)b * NN * UU;
    const unsigned short* Vb = Vt + (size_t)b * UU * NN;

    for (int kt = 0; kt < NN; kt += 64) {
        // ---- S = Q K^T : wave computes 16 q-rows x 32 keys (2 key tiles)
        floatx4 s0 = {}, s1 = {};
        const unsigned short* kp0 = Kb + (size_t)(kt + kh * 32 + l16) * UU + quad * 8;
        const unsigned short* kp1 = kp0 + 16 * UU;
        #pragma unroll
        for (int kk = 0; kk < 16; kk++) {
            short8 b0 = *(const short8*)(kp0 + kk * 32);
            short8 b1 = *(const short8*)(kp1 + kk * 32);
            s0 = mfma16(qf[kk], b0, s0);
            s1 = mfma16(qf[kk], b1, s1);
        }
        #pragma unroll
        for (int i = 0; i < 4; i++) {
            S_lds[(qt * 16 + quad * 4 + i) * 68 + kh * 32 + l16]      = s0[i] * sscale;
            S_lds[(qt * 16 + quad * 4 + i) * 68 + kh * 32 + 16 + l16] = s1[i] * sscale;
        }
        __syncthreads();

        // ---- online softmax stats (8 threads per row, 8 cols each)
        {
            const int row = t >> 3, c8 = (t & 7) * 8;
            const float4* sp = (const float4*)(S_lds + row * 68 + c8);
            float4 va = sp[0], vb = sp[1];
            float mx = fmaxf(fmaxf(fmaxf(va.x, va.y), fmaxf(va.z, va.w)),
                             fmaxf(fmaxf(vb.x, vb.y), fmaxf(vb.z, vb.w)));
            mx = fmaxf(mx, __shfl_xor(mx, 1, 8));
            mx = fmaxf(mx, __shfl_xor(mx, 2, 8));
            mx = fmaxf(mx, __shfl_xor(mx, 4, 8));
            const float m_old = m_lds[row];
            const float m_new = fmaxf(m_old, mx);
            float p[8] = { exp2f(va.x - m_new), exp2f(va.y - m_new),
                           exp2f(va.z - m_new), exp2f(va.w - m_new),
                           exp2f(vb.x - m_new), exp2f(vb.y - m_new),
                           exp2f(vb.z - m_new), exp2f(vb.w - m_new) };
            short8 pv; float sum = 0.f;
            #pragma unroll
            for (int j = 0; j < 8; j++) {
                unsigned short us = f2bf(p[j]);
                pv[j] = (short)us;
                sum += bf2f(us);   // sum what PV actually uses
            }
            *(short8*)(P_lds + row * 72 + c8) = pv;
            sum += __shfl_xor(sum, 1, 8);
            sum += __shfl_xor(sum, 2, 8);
            sum += __shfl_xor(sum, 4, 8);
            if ((t & 7) == 0) {
                const float alpha = exp2f(m_old - m_new);
                a_lds[row] = alpha;
                m_lds[row] = m_new;
                l_lds[row] = l_lds[row] * alpha + sum;
            }
        }
        __syncthreads();

        // ---- O = O*alpha + P @ V : wave does 16 q-rows x 256 dims (dh half)
        float al[4];
        #pragma unroll
        for (int i = 0; i < 4; i++) al[i] = a_lds[qt * 16 + quad * 4 + i];
        #pragma unroll
        for (int dt = 0; dt < 16; dt++)
            #pragma unroll
            for (int i = 0; i < 4; i++) o[dt][i] *= al[i];
        const short8 a0 = *(const short8*)(P_lds + (qt * 16 + l16) * 72 + quad * 8);
        const short8 a1 = *(const short8*)(P_lds + (qt * 16 + l16) * 72 + 32 + quad * 8);
        #pragma unroll
        for (int dt = 0; dt < 16; dt++) {
            const unsigned short* vp = Vb + (size_t)(dh * 256 + dt * 16 + l16) * NN + kt + quad * 8;
            short8 b0 = *(const short8*)(vp);
            short8 b1 = *(const short8*)(vp + 32);
            o[dt] = mfma16(a0, b0, o[dt]);
            o[dt] = mfma16(a1, b1, o[dt]);
        }
    }

    // ---- epilogue: normalize, store ctx bf16 [B*N][U]
    float linv[4];
    #pragma unroll
    for (int i = 0; i < 4; i++) linv[i] = 1.f / l_lds[qt * 16 + quad * 4 + i];
    #pragma unroll
    for (int dt = 0; dt < 16; dt++) {
        const int d = dh * 256 + dt * 16 + l16;
        #pragma unroll
        for (int i = 0; i < 4; i++)
            ctx[(size_t)(b * NN + q0 + qt * 16 + quad * 4 + i) * UU + d] = f2bf(o[dt][i] * linv[i]);
    }
}

// ---------------------------------------------------------------- out proj + residual
__global__ void __launch_bounds__(256, 2) k_out(
    const unsigned short* __restrict__ Cx,
    const unsigned short* __restrict__ WpT,
    const float* __restrict__ bp,
    const float* __restrict__ x,
    float* __restrict__ out)
{
    __shared__ __align__(16) unsigned short As[128 * 32];
    __shared__ __align__(16) unsigned short Bs[128 * 32];
    const int t = threadIdx.x, wave = t >> 6, lane = t & 63;
    const int quad = lane >> 4, l16 = lane & 15;
    const int m0 = blockIdx.x * 128, n0 = blockIdx.y * 128;
    const int wm = wave >> 1, wn = wave & 1;
    const int srow = wave * 32 + (lane >> 2);
    const int scol = (lane & 3) * 8;
    const unsigned short* gA = Cx + (size_t)(m0 + srow) * UU + scol;
    const unsigned short* gB = WpT + (size_t)(n0 + srow) * UU + scol;
    unsigned short* lA = As + wave * 1024;
    unsigned short* lB = Bs + wave * 1024;

    floatx4 acc[4][4] = {};

    for (int k0 = 0; k0 < UU; k0 += 32) {
        GLL16(gA + k0, lA);
        GLL16(gA + k0 + 16 * UU, lA + 512);
        GLL16(gB + k0, lB);
        GLL16(gB + k0 + 16 * UU, lB + 512);
        __syncthreads();
        short8 a[4], b[4];
        #pragma unroll
        for (int i = 0; i < 4; i++)
            a[i] = *(const short8*)(As + (wm * 64 + i * 16 + l16) * 32 + quad * 8);
        #pragma unroll
        for (int j = 0; j < 4; j++)
            b[j] = *(const short8*)(Bs + (wn * 64 + j * 16 + l16) * 32 + quad * 8);
        #pragma unroll
        for (int i = 0; i < 4; i++)
            #pragma unroll
            for (int j = 0; j < 4; j++)
                acc[i][j] = mfma16(a[i], b[j], acc[i][j]);
        __syncthreads();
    }

    #pragma unroll
    for (int j = 0; j < 4; j++) {
        const int n = n0 + wn * 64 + j * 16 + l16;
        const float bv_ = bp[n];
        #pragma unroll
        for (int i = 0; i < 4; i++) {
            const int mb = m0 + wm * 64 + i * 16 + quad * 4;
            #pragma unroll
            for (int r = 0; r < 4; r++) {
                const size_t idx = (size_t)(mb + r) * UU + n;
                out[idx] = acc[i][j][r] + bv_ + x[idx];
            }
        }
    }
}

// ---------------------------------------------------------------- launch
extern "C" void kernel_launch(void* const* d_in, const int* in_sizes, int n_in,
                              void* d_out, int out_size, void* d_ws, size_t ws_size,
                              hipStream_t stream)
{
    const float* x  = (const float*)d_in[0];
    const float* Wq = (const float*)d_in[1];
    const float* bq = (const float*)d_in[2];
    const float* Wk = (const float*)d_in[3];
    const float* bk = (const float*)d_in[4];
    const float* Wv = (const float*)d_in[5];
    const float* bv = (const float*)d_in[6];
    const float* Wp = (const float*)d_in[7];
    const float* bp = (const float*)d_in[8];
    float* out = (float*)d_out;

    char* ws = (char*)d_ws;
    unsigned short* Xb  = (unsigned short*)(ws);              // 16 MB  bf16 x
    unsigned short* WqT = (unsigned short*)(ws + 16777216);   // 512 KB each
    unsigned short* WkT = (unsigned short*)(ws + 17301504);
    unsigned short* WvT = (unsigned short*)(ws + 17825792);
    unsigned short* WpT = (unsigned short*)(ws + 18350080);
    unsigned short* Qm  = (unsigned short*)(ws + 18874368);   // 16 MB [B*N][U]
    unsigned short* Km  = (unsigned short*)(ws + 35651584);   // 16 MB [B*N][U]
    unsigned short* Vt  = (unsigned short*)(ws + 52428800);   // 16 MB [B][U][N]
    unsigned short* Cx  = (unsigned short*)(ws + 69206016);   // 16 MB [B*N][U]

    hipLaunchKernelGGL(k_cvt_x, dim3(8192), dim3(256), 0, stream, x, Xb);
    hipLaunchKernelGGL(k_cvt_w, dim3(1024), dim3(256), 0, stream, Wq, WqT);
    hipLaunchKernelGGL(k_cvt_w, dim3(1024), dim3(256), 0, stream, Wk, WkT);
    hipLaunchKernelGGL(k_cvt_w, dim3(1024), dim3(256), 0, stream, Wv, WvT);
    hipLaunchKernelGGL(k_cvt_w, dim3(1024), dim3(256), 0, stream, Wp, WpT);
    hipLaunchKernelGGL(k_proj, dim3(128, 4, 3), dim3(256), 0, stream,
                       Xb, WqT, WkT, WvT, bq, bk, bv, Qm, Km, Vt);
    hipLaunchKernelGGL(k_flash, dim3(64, 4), dim3(512), 0, stream, Qm, Km, Vt, Cx);
    hipLaunchKernelGGL(k_out, dim3(128, 4), dim3(256), 0, stream, Cx, WpT, bp, x, out);
}

// Round 2
// 374.615 us; speedup vs baseline: 3.0272x; 3.0272x over previous
//
#include <hip/hip_runtime.h>
#include <hip/hip_bf16.h>
#include <math.h>

#define NB 4
#define NN 4096
#define UU 512

using short8  = __attribute__((ext_vector_type(8))) short;
using bf16x8  = __attribute__((ext_vector_type(8))) __bf16;
using floatx4 = __attribute__((ext_vector_type(4))) float;

__device__ __forceinline__ floatx4 mfma16(short8 a, short8 b, floatx4 c) {
    return __builtin_amdgcn_mfma_f32_16x16x32_bf16(
        __builtin_bit_cast(bf16x8, a), __builtin_bit_cast(bf16x8, b), c, 0, 0, 0);
}

__device__ __forceinline__ unsigned short f2bf(float f) {
    union { float f; unsigned u; } v; v.f = f;
    return (unsigned short)((v.u + 0x7fffu + ((v.u >> 16) & 1u)) >> 16);
}
__device__ __forceinline__ float bf2f(unsigned short s) {
    union { unsigned u; float f; } v; v.u = ((unsigned)s) << 16; return v.f;
}

#define GLL16(gp, lp) __builtin_amdgcn_global_load_lds( \
    (const __attribute__((address_space(1))) void*)(gp), \
    (__attribute__((address_space(3))) void*)(lp), 16, 0, 0)

// ---------------------------------------------------------------- converts
__global__ void __launch_bounds__(256) k_cvt_x(const float* __restrict__ x,
                                               unsigned short* __restrict__ xb) {
    int i = (blockIdx.x * 256 + threadIdx.x) * 4;
    float4 v = *(const float4*)(x + i);
    ushort4 o;
    o.x = f2bf(v.x); o.y = f2bf(v.y); o.z = f2bf(v.z); o.w = f2bf(v.w);
    *(ushort4*)(xb + i) = o;
}

// WT[n*512+k] = bf16(W[k*512+n])
__global__ void __launch_bounds__(256) k_cvt_w(const float* __restrict__ W,
                                               unsigned short* __restrict__ WT) {
    int idx = blockIdx.x * 256 + threadIdx.x;  // 0..262143
    int n = idx >> 9, k = idx & 511;
    WT[idx] = f2bf(W[k * 512 + n]);
}

// ---------------------------------------------------------------- QKV proj
// C = Xb @ W (A.B^T form with WT), 128x128 tile, BK=32.
// z=0: Q row-major [b*N][U]
// z=1: K8 layout [b][d>>3][key][d&7]   (flash K-tile staging friendly)
// z=2: V8 layout [b][key>>3][d][key&7] (flash V-tile staging friendly)
__global__ void __launch_bounds__(256, 2) k_proj(
    const unsigned short* __restrict__ Xb,
    const unsigned short* __restrict__ WqT, const unsigned short* __restrict__ WkT,
    const unsigned short* __restrict__ WvT,
    const float* __restrict__ bq, const float* __restrict__ bk, const float* __restrict__ bv,
    unsigned short* __restrict__ Q, unsigned short* __restrict__ K8,
    unsigned short* __restrict__ V8)
{
    __shared__ __align__(16) unsigned short As[128 * 32];
    __shared__ __align__(16) unsigned short Bs[128 * 32];
    const int z = blockIdx.z;
    const unsigned short* WT = (z == 0) ? WqT : (z == 1) ? WkT : WvT;
    const float* bias = (z == 0) ? bq : (z == 1) ? bk : bv;
    const int t = threadIdx.x, wave = t >> 6, lane = t & 63;
    const int quad = lane >> 4, l16 = lane & 15;
    const int m0 = blockIdx.x * 128, n0 = blockIdx.y * 128;
    const int wm = wave >> 1, wn = wave & 1;

    const int srow = wave * 32 + (lane >> 2);
    const int scol = (lane & 3) * 8;
    const unsigned short* gA = Xb + (size_t)(m0 + srow) * UU + scol;
    const unsigned short* gB = WT + (size_t)(n0 + srow) * UU + scol;
    unsigned short* lA = As + wave * 1024;
    unsigned short* lB = Bs + wave * 1024;

    floatx4 acc[4][4] = {};

    for (int k0 = 0; k0 < UU; k0 += 32) {
        GLL16(gA + k0, lA);
        GLL16(gA + k0 + 16 * UU, lA + 512);
        GLL16(gB + k0, lB);
        GLL16(gB + k0 + 16 * UU, lB + 512);
        __syncthreads();
        short8 a[4], b[4];
        #pragma unroll
        for (int i = 0; i < 4; i++)
            a[i] = *(const short8*)(As + (wm * 64 + i * 16 + l16) * 32 + quad * 8);
        #pragma unroll
        for (int j = 0; j < 4; j++)
            b[j] = *(const short8*)(Bs + (wn * 64 + j * 16 + l16) * 32 + quad * 8);
        #pragma unroll
        for (int i = 0; i < 4; i++)
            #pragma unroll
            for (int j = 0; j < 4; j++)
                acc[i][j] = mfma16(a[i], b[j], acc[i][j]);
        __syncthreads();
    }

    #pragma unroll
    for (int j = 0; j < 4; j++) {
        const int n = n0 + wn * 64 + j * 16 + l16;
        const float bv_ = bias[n];
        #pragma unroll
        for (int i = 0; i < 4; i++) {
            const int mb = m0 + wm * 64 + i * 16 + quad * 4;
            const int bb = mb >> 12, tok = mb & (NN - 1);
            if (z == 0) {
                #pragma unroll
                for (int r = 0; r < 4; r++)
                    Q[(size_t)(mb + r) * UU + n] = f2bf(acc[i][j][r] + bv_);
            } else if (z == 1) {
                const size_t base = (size_t)bb * NN * UU + (size_t)(n >> 3) * (NN * 8)
                                  + (size_t)tok * 8 + (n & 7);
                #pragma unroll
                for (int r = 0; r < 4; r++)
                    K8[base + (size_t)r * 8] = f2bf(acc[i][j][r] + bv_);
            } else {
                ushort4 o;
                o.x = f2bf(acc[i][j][0] + bv_);
                o.y = f2bf(acc[i][j][1] + bv_);
                o.z = f2bf(acc[i][j][2] + bv_);
                o.w = f2bf(acc[i][j][3] + bv_);
                *(ushort4*)(V8 + (size_t)bb * NN * UU + (size_t)(tok >> 3) * (UU * 8)
                            + (size_t)n * 8 + (tok & 7)) = o;
            }
        }
    }
}

// ---------------------------------------------------------------- flash attention
// 8 waves: wave = (qt 0..3, kh/dh 0..1). BM=64 q rows/block, BN=64 keys/iter.
// K tile + V tile staged in LDS via global_load_lds, software-pipelined:
//   V(kt) issued at loop top  (drains at post-S barrier, hidden behind S)
//   K(kt+64) issued after stats barrier (drains at loop-end barrier, hidden behind PV)
__global__ void __launch_bounds__(512, 1) k_flash(
    const unsigned short* __restrict__ Q,
    const unsigned short* __restrict__ K8,
    const unsigned short* __restrict__ V8,
    unsigned short* __restrict__ ctx)
{
    __shared__ __align__(16) unsigned short Ks[64 * 64 * 8];  // [dc 64][key 64][kk 8]  64 KB
    __shared__ __align__(16) unsigned short Vs[8 * 512 * 8];  // [kc 8][d 512][kk 8]    64 KB
    __shared__ __align__(16) float S_lds[64 * 68];
    __shared__ __align__(16) unsigned short P_lds[64 * 72];
    __shared__ float m_lds[64], l_lds[64], a_lds[64];

    const int b = blockIdx.y;
    const int q0 = blockIdx.x * 64;
    const int t = threadIdx.x;
    const int wave = t >> 6, lane = t & 63, quad = lane >> 4, l16 = lane & 15;
    const int qt = wave >> 1;   // q-tile 0..3
    const int kh = wave & 1;    // key half for S
    const int dh = wave & 1;    // d half for PV

    if (t < 64) { m_lds[t] = -INFINITY; l_lds[t] = 0.f; }

    // Q fragments for this wave's 16 q-rows, all 512 dims (64 VGPR)
    const unsigned short* qp = Q + (size_t)(b * NN + q0 + qt * 16 + l16) * UU + quad * 8;
    short8 qf[16];
    #pragma unroll
    for (int kk = 0; kk < 16; kk++) qf[kk] = *(const short8*)(qp + kk * 32);

    const unsigned short* K8b = K8 + (size_t)b * NN * UU;
    const unsigned short* V8b = V8 + (size_t)b * NN * UU;

    // prologue: stage K(0)
    #pragma unroll
    for (int j = 0; j < 8; j++) {
        const int dc = wave * 8 + j;
        GLL16(K8b + (size_t)dc * (NN * 8) + lane * 8, Ks + dc * 512 + lane * 8);
    }

    floatx4 o[16] = {};
    const float sscale = 0.04419417382415922f * 1.4426950408889634f;  // 1/sqrt(512)*log2(e)

    __syncthreads();  // K(0) staged, m/l init visible

    for (int kt = 0; kt < NN; kt += 64) {
        // stage V(kt): contiguous 64 KB at V8b + kt*512 (prev PV done at loop-end barrier)
        #pragma unroll
        for (int j = 0; j < 8; j++) {
            const int c = wave * 8 + j;
            GLL16(V8b + (size_t)kt * 512 + (size_t)c * 512 + lane * 8, Vs + c * 512 + lane * 8);
        }

        // ---- S = Q K^T from LDS: wave computes 16 q-rows x 32 keys
        floatx4 s0 = {}, s1 = {};
        #pragma unroll
        for (int kk = 0; kk < 16; kk++) {
            const unsigned short* kb = Ks + (kk * 4 + quad) * 512 + (kh * 32 + l16) * 8;
            short8 b0 = *(const short8*)(kb);
            short8 b1 = *(const short8*)(kb + 128);   // +16 keys
            s0 = mfma16(qf[kk], b0, s0);
            s1 = mfma16(qf[kk], b1, s1);
        }
        #pragma unroll
        for (int i = 0; i < 4; i++) {
            S_lds[(qt * 16 + quad * 4 + i) * 68 + kh * 32 + l16]      = s0[i] * sscale;
            S_lds[(qt * 16 + quad * 4 + i) * 68 + kh * 32 + 16 + l16] = s1[i] * sscale;
        }
        __syncthreads();   // S visible; V(kt) drained

        // ---- online softmax stats (8 threads per row, 8 cols each)
        {
            const int row = t >> 3, c8 = (t & 7) * 8;
            const float4* sp = (const float4*)(S_lds + row * 68 + c8);
            float4 va = sp[0], vb = sp[1];
            float mx = fmaxf(fmaxf(fmaxf(va.x, va.y), fmaxf(va.z, va.w)),
                             fmaxf(fmaxf(vb.x, vb.y), fmaxf(vb.z, vb.w)));
            mx = fmaxf(mx, __shfl_xor(mx, 1, 8));
            mx = fmaxf(mx, __shfl_xor(mx, 2, 8));
            mx = fmaxf(mx, __shfl_xor(mx, 4, 8));
            const float m_old = m_lds[row];
            const float m_new = fmaxf(m_old, mx);
            float p[8] = { exp2f(va.x - m_new), exp2f(va.y - m_new),
                           exp2f(va.z - m_new), exp2f(va.w - m_new),
                           exp2f(vb.x - m_new), exp2f(vb.y - m_new),
                           exp2f(vb.z - m_new), exp2f(vb.w - m_new) };
            short8 pv; float sum = 0.f;
            #pragma unroll
            for (int j = 0; j < 8; j++) {
                unsigned short us = f2bf(p[j]);
                pv[j] = (short)us;
                sum += bf2f(us);   // sum what PV actually uses
            }
            *(short8*)(P_lds + row * 72 + c8) = pv;
            sum += __shfl_xor(sum, 1, 8);
            sum += __shfl_xor(sum, 2, 8);
            sum += __shfl_xor(sum, 4, 8);
            if ((t & 7) == 0) {
                const float alpha = exp2f(m_old - m_new);
                a_lds[row] = alpha;
                m_lds[row] = m_new;
                l_lds[row] = l_lds[row] * alpha + sum;
            }
        }
        __syncthreads();   // P/stats visible; Ks reads done

        // stage K(kt+64) — drains at loop-end barrier, hidden behind PV
        if (kt + 64 < NN) {
            #pragma unroll
            for (int j = 0; j < 8; j++) {
                const int dc = wave * 8 + j;
                GLL16(K8b + (size_t)dc * (NN * 8) + (size_t)(kt + 64 + lane) * 8,
                      Ks + dc * 512 + lane * 8);
            }
        }

        // ---- O = O*alpha + P @ V from LDS: wave does 16 q-rows x 256 dims (dh half)
        float al[4];
        #pragma unroll
        for (int i = 0; i < 4; i++) al[i] = a_lds[qt * 16 + quad * 4 + i];
        #pragma unroll
        for (int dt = 0; dt < 16; dt++)
            #pragma unroll
            for (int i = 0; i < 4; i++) o[dt][i] *= al[i];
        const short8 a0 = *(const short8*)(P_lds + (qt * 16 + l16) * 72 + quad * 8);
        const short8 a1 = *(const short8*)(P_lds + (qt * 16 + l16) * 72 + 32 + quad * 8);
        #pragma unroll
        for (int dt = 0; dt < 16; dt++) {
            const int d = dh * 256 + dt * 16 + l16;
            short8 b0 = *(const short8*)(Vs + quad * 4096 + d * 8);
            short8 b1 = *(const short8*)(Vs + (4 + quad) * 4096 + d * 8);
            o[dt] = mfma16(a0, b0, o[dt]);
            o[dt] = mfma16(a1, b1, o[dt]);
        }
        __syncthreads();   // PV reads done; K(kt+64) drained
    }

    // ---- epilogue: normalize, store ctx bf16 [B*N][U]
    float linv[4];
    #pragma unroll
    for (int i = 0; i < 4; i++) linv[i] = 1.f / l_lds[qt * 16 + quad * 4 + i];
    #pragma unroll
    for (int dt = 0; dt < 16; dt++) {
        const int d = dh * 256 + dt * 16 + l16;
        #pragma unroll
        for (int i = 0; i < 4; i++)
            ctx[(size_t)(b * NN + q0 + qt * 16 + quad * 4 + i) * UU + d] = f2bf(o[dt][i] * linv[i]);
    }
}

// ---------------------------------------------------------------- out proj + residual
__global__ void __launch_bounds__(256, 2) k_out(
    const unsigned short* __restrict__ Cx,
    const unsigned short* __restrict__ WpT,
    const float* __restrict__ bp,
    const float* __restrict__ x,
    float* __restrict__ out)
{
    __shared__ __align__(16) unsigned short As[128 * 32];
    __shared__ __align__(16) unsigned short Bs[128 * 32];
    const int t = threadIdx.x, wave = t >> 6, lane = t & 63;
    const int quad = lane >> 4, l16 = lane & 15;
    const int m0 = blockIdx.x * 128, n0 = blockIdx.y * 128;
    const int wm = wave >> 1, wn = wave & 1;
    const int srow = wave * 32 + (lane >> 2);
    const int scol = (lane & 3) * 8;
    const unsigned short* gA = Cx + (size_t)(m0 + srow) * UU + scol;
    const unsigned short* gB = WpT + (size_t)(n0 + srow) * UU + scol;
    unsigned short* lA = As + wave * 1024;
    unsigned short* lB = Bs + wave * 1024;

    floatx4 acc[4][4] = {};

    for (int k0 = 0; k0 < UU; k0 += 32) {
        GLL16(gA + k0, lA);
        GLL16(gA + k0 + 16 * UU, lA + 512);
        GLL16(gB + k0, lB);
        GLL16(gB + k0 + 16 * UU, lB + 512);
        __syncthreads();
        short8 a[4], b[4];
        #pragma unroll
        for (int i = 0; i < 4; i++)
            a[i] = *(const short8*)(As + (wm * 64 + i * 16 + l16) * 32 + quad * 8);
        #pragma unroll
        for (int j = 0; j < 4; j++)
            b[j] = *(const short8*)(Bs + (wn * 64 + j * 16 + l16) * 32 + quad * 8);
        #pragma unroll
        for (int i = 0; i < 4; i++)
            #pragma unroll
            for (int j = 0; j < 4; j++)
                acc[i][j] = mfma16(a[i], b[j], acc[i][j]);
        __syncthreads();
    }

    #pragma unroll
    for (int j = 0; j < 4; j++) {
        const int n = n0 + wn * 64 + j * 16 + l16;
        const float bv_ = bp[n];
        #pragma unroll
        for (int i = 0; i < 4; i++) {
            const int mb = m0 + wm * 64 + i * 16 + quad * 4;
            #pragma unroll
            for (int r = 0; r < 4; r++) {
                const size_t idx = (size_t)(mb + r) * UU + n;
                out[idx] = acc[i][j][r] + bv_ + x[idx];
            }
        }
    }
}

// ---------------------------------------------------------------- launch
extern "C" void kernel_launch(void* const* d_in, const int* in_sizes, int n_in,
                              void* d_out, int out_size, void* d_ws, size_t ws_size,
                              hipStream_t stream)
{
    const float* x  = (const float*)d_in[0];
    const float* Wq = (const float*)d_in[1];
    const float* bq = (const float*)d_in[2];
    const float* Wk = (const float*)d_in[3];
    const float* bk = (const float*)d_in[4];
    const float* Wv = (const float*)d_in[5];
    const float* bv = (const float*)d_in[6];
    const float* Wp = (const float*)d_in[7];
    const float* bp = (const float*)d_in[8];
    float* out = (float*)d_out;

    char* ws = (char*)d_ws;
    unsigned short* Xb  = (unsigned short*)(ws);              // 16 MB  bf16 x
    unsigned short* WqT = (unsigned short*)(ws + 16777216);   // 512 KB each
    unsigned short* WkT = (unsigned short*)(ws + 17301504);
    unsigned short* WvT = (unsigned short*)(ws + 17825792);
    unsigned short* WpT = (unsigned short*)(ws + 18350080);
    unsigned short* Qm  = (unsigned short*)(ws + 18874368);   // 16 MB [b*N][U]
    unsigned short* K8m = (unsigned short*)(ws + 35651584);   // 16 MB [b][d>>3][key][d&7]
    unsigned short* V8m = (unsigned short*)(ws + 52428800);   // 16 MB [b][key>>3][d][key&7]
    unsigned short* Cx  = (unsigned short*)(ws + 69206016);   // 16 MB [b*N][U]

    hipLaunchKernelGGL(k_cvt_x, dim3(8192), dim3(256), 0, stream, x, Xb);
    hipLaunchKernelGGL(k_cvt_w, dim3(1024), dim3(256), 0, stream, Wq, WqT);
    hipLaunchKernelGGL(k_cvt_w, dim3(1024), dim3(256), 0, stream, Wk, WkT);
    hipLaunchKernelGGL(k_cvt_w, dim3(1024), dim3(256), 0, stream, Wv, WvT);
    hipLaunchKernelGGL(k_cvt_w, dim3(1024), dim3(256), 0, stream, Wp, WpT);
    hipLaunchKernelGGL(k_proj, dim3(128, 4, 3), dim3(256), 0, stream,
                       Xb, WqT, WkT, WvT, bq, bk, bv, Qm, K8m, V8m);
    hipLaunchKernelGGL(k_flash, dim3(64, 4), dim3(512), 0, stream, Qm, K8m, V8m, Cx);
    hipLaunchKernelGGL(k_out, dim3(128, 4), dim3(256), 0, stream, Cx, WpT, bp, x, out);
}